// Round 11
// baseline (149.876 us; speedup 1.0000x reference)
//
#include <hip/hip_runtime.h>
#include <math.h>

#define NS 4
#define HDIM 1024
#define DDIM 4096           // NS*HDIM
#define TA 8                // tokens per block in mhc_gates
#define HC_EPS_F 1e-6f
#define NORM_EPS_F 1e-6f

__device__ __forceinline__ float frcp(float v) { return __builtin_amdgcn_rcpf(v); }

// ============ K1: dots + sinkhorn -> gates[tok][24]. Full 1-deep x+fn prefetch,
// UNCAPPED registers: (256,1). Toolchain law (measured R7/R8/R9/R10):
// launch_bounds 2nd arg -> VGPR cap = 256/arg; caps below ~180 serialize the
// 14 in-flight loads (the 86-95us plateau) or spill (R8/R9). Demand ~180 fits 256.
__launch_bounds__(256, 1)
__global__ void mhc_gates(const float* __restrict__ x,
                          const float* __restrict__ hc_fn,
                          const float* __restrict__ hc_scale,
                          const float* __restrict__ hc_base,
                          float* __restrict__ gates) {
  __shared__ float w_s[25][TA];        // 24 weights + ssq per token (800 B)

  const int tid  = threadIdx.x;
  const int lane = tid & 63;
  const int wave = tid >> 6;
  const long long tok0 = (long long)blockIdx.x * TA;

  const float4* xb[TA];                // block-uniform bases -> SGPR-friendly
  #pragma unroll
  for (int t = 0; t < TA; ++t)
    xb[t] = (const float4*)(x + (tok0 + t) * DDIM);

  const int mb = wave * 6;             // wave owns m in [6w, 6w+6)
  const float4* fn4[6];
  #pragma unroll
  for (int m = 0; m < 6; ++m)
    fn4[m] = (const float4*)(hc_fn + (long long)(mb + m) * DDIM);

  float acc[6][TA];
  #pragma unroll
  for (int m = 0; m < 6; ++m)
    #pragma unroll
    for (int t = 0; t < TA; ++t) acc[m][t] = 0.f;
  float ss0 = 0.f, ss1 = 0.f;          // wave w owns ssq of tokens w and w+4

  // preload iteration 0 (x and fn)
  float4 c_x[TA], c_f[6];
  #pragma unroll
  for (int t = 0; t < TA; ++t) c_x[t] = xb[t][lane];
  #pragma unroll
  for (int m = 0; m < 6; ++m) c_f[m] = fn4[m][lane];

  #pragma unroll 2
  for (int it = 0; it < 16; ++it) {
    // issue ALL of next iteration's loads first (14 in flight across the FMA block)
    float4 n_x[TA], n_f[6];
    if (it < 15) {
      const int nfl = it * 64 + 64 + lane;
      #pragma unroll
      for (int t = 0; t < TA; ++t) n_x[t] = xb[t][nfl];
      #pragma unroll
      for (int m = 0; m < 6; ++m) n_f[m] = fn4[m][nfl];
    }
    #pragma unroll
    for (int t = 0; t < TA; ++t) {
      if (wave == (t & 3)) {           // compile-time t, wave-uniform branch
        float s = fmaf(c_x[t].x, c_x[t].x, fmaf(c_x[t].y, c_x[t].y,
                  fmaf(c_x[t].z, c_x[t].z, c_x[t].w * c_x[t].w)));
        if (t < 4) ss0 += s; else ss1 += s;
      }
      #pragma unroll
      for (int m = 0; m < 6; ++m)
        acc[m][t] = fmaf(c_x[t].x, c_f[m].x,
                    fmaf(c_x[t].y, c_f[m].y,
                    fmaf(c_x[t].z, c_f[m].z,
                    fmaf(c_x[t].w, c_f[m].w, acc[m][t]))));
    }
    if (it < 15) {
      #pragma unroll
      for (int t = 0; t < TA; ++t) c_x[t] = n_x[t];
      #pragma unroll
      for (int m = 0; m < 6; ++m) c_f[m] = n_f[m];
    }
  }

  // butterfly reduce -> LDS
  #pragma unroll
  for (int m = 0; m < 6; ++m)
    #pragma unroll
    for (int t = 0; t < TA; ++t) {
      float v = acc[m][t];
      #pragma unroll
      for (int off = 32; off > 0; off >>= 1) v += __shfl_xor(v, off, 64);
      if (lane == 0) w_s[mb + m][t] = v;
    }
  {
    float v0 = ss0, v1 = ss1;
    #pragma unroll
    for (int off = 32; off > 0; off >>= 1) {
      v0 += __shfl_xor(v0, off, 64);
      v1 += __shfl_xor(v1, off, 64);
    }
    if (lane == 0) { w_s[24][wave] = v0; w_s[24][wave + 4] = v1; }
  }
  __syncthreads();

  // sinkhorn + gates on waves 0-1: 16 lanes per token, 4 tokens per wave
  if (wave < 2) {
    const int tt = wave * 4 + (lane >> 4);
    const int e  = lane & 15;          // i*4 + j
    const float rs = rsqrtf(w_s[24][tt] * (1.0f / DDIM) + NORM_EPS_F);
    const float s0 = hc_scale[0], s1 = hc_scale[1], s2 = hc_scale[2];

    float h = w_s[8 + e][tt] * rs * s2 + hc_base[8 + e];
    // row softmax over j (quad shuffles) + eps
    float mx = fmaxf(h, __shfl_xor(h, 1, 4));
    mx = fmaxf(mx, __shfl_xor(mx, 2, 4));
    float ex = expf(h - mx);
    float sm = ex + __shfl_xor(ex, 1, 4);
    sm += __shfl_xor(sm, 2, 4);
    h = ex * frcp(sm) + HC_EPS_F;
    // column normalize (sum over i: xor 4,8 within 16)
    float cs = h + __shfl_xor(h, 4, 16);
    cs += __shfl_xor(cs, 8, 16);
    h *= frcp(cs + HC_EPS_F);
    #pragma unroll 1
    for (int itn = 0; itn < 19; ++itn) {
      float rsum = h + __shfl_xor(h, 1, 4);
      rsum += __shfl_xor(rsum, 2, 4);
      h *= frcp(rsum + HC_EPS_F);
      float csum = h + __shfl_xor(h, 4, 16);
      csum += __shfl_xor(csum, 8, 16);
      h *= frcp(csum + HC_EPS_F);
    }
    float* g = gates + (tok0 + tt) * 24;
    g[8 + e] = h;
    if (e < NS) {
      const float wp = w_s[e][tt] * rs;
      g[e] = frcp(1.0f + expf(-(wp * s0 + hc_base[e]))) + HC_EPS_F;
      const float wq = w_s[NS + e][tt] * rs;
      g[NS + e] = 2.0f * frcp(1.0f + expf(-(wq * s1 + hc_base[NS + e])));
    }
  }
}

// ============ K2: gates + x -> out (pure stream, at write roofline ~21us) ============
__launch_bounds__(256, 8)
__global__ void mhc_out(const float* __restrict__ x,
                        const float* __restrict__ gates,
                        float* __restrict__ out) {
  const long long token = blockIdx.x;
  const int q = threadIdx.x;           // float4 index in [0,256)

  const float* g = gates + token * 24; // uniform address -> scalar loads
  float hp[NS], hq[NS], hr[NS][NS];
  #pragma unroll
  for (int i = 0; i < NS; ++i) {
    hp[i] = g[i];
    hq[i] = g[NS + i];
    #pragma unroll
    for (int j = 0; j < NS; ++j) hr[i][j] = g[8 + i * NS + j];
  }

  const float4* xb = (const float4*)(x + token * DDIM);
  float4 xv[NS];
  #pragma unroll
  for (int i = 0; i < NS; ++i) xv[i] = xb[i * 256 + q];

  float4 y;
  y.x = hp[0]*xv[0].x + hp[1]*xv[1].x + hp[2]*xv[2].x + hp[3]*xv[3].x;
  y.y = hp[0]*xv[0].y + hp[1]*xv[1].y + hp[2]*xv[2].y + hp[3]*xv[3].y;
  y.z = hp[0]*xv[0].z + hp[1]*xv[1].z + hp[2]*xv[2].z + hp[3]*xv[3].z;
  y.w = hp[0]*xv[0].w + hp[1]*xv[1].w + hp[2]*xv[2].w + hp[3]*xv[3].w;

  float4* ob = (float4*)(out + token * DDIM);
  #pragma unroll
  for (int n = 0; n < NS; ++n) {
    float4 o;
    o.x = hq[n]*y.x + hr[0][n]*xv[0].x + hr[1][n]*xv[1].x + hr[2][n]*xv[2].x + hr[3][n]*xv[3].x;
    o.y = hq[n]*y.y + hr[0][n]*xv[0].y + hr[1][n]*xv[1].y + hr[2][n]*xv[2].y + hr[3][n]*xv[3].y;
    o.z = hq[n]*y.z + hr[0][n]*xv[0].z + hr[1][n]*xv[1].z + hr[2][n]*xv[2].z + hr[3][n]*xv[3].z;
    o.w = hq[n]*y.w + hr[0][n]*xv[0].w + hr[1][n]*xv[1].w + hr[2][n]*xv[2].w + hr[3][n]*xv[3].w;
    ob[n * 256 + q] = o;
  }
}

extern "C" void kernel_launch(void* const* d_in, const int* in_sizes, int n_in,
                              void* d_out, int out_size, void* d_ws, size_t ws_size,
                              hipStream_t stream) {
  const float* x        = (const float*)d_in[0];
  const float* hc_fn    = (const float*)d_in[1];
  const float* hc_scale = (const float*)d_in[2];
  const float* hc_base  = (const float*)d_in[3];
  float* out   = (float*)d_out;
  float* gates = (float*)d_ws;         // ntok*24*4 = 786 KB (proven within ws_size)

  const int ntok = in_sizes[0] / DDIM; // B*S = 8192
  mhc_gates<<<ntok / TA, 256, 0, stream>>>(x, hc_fn, hc_scale, hc_base, gates);
  mhc_out<<<ntok, 256, 0, stream>>>(x, gates, out);
}

// Round 12
// 130.211 us; speedup vs baseline: 1.1510x; 1.1510x over previous
//
#include <hip/hip_runtime.h>
#include <math.h>

#define NS 4
#define HDIM 1024
#define DDIM 4096           // NS*HDIM
#define MT 16               // tokens per M-tile (one wave-block)
#define KCH 512             // K-chunk per block
#define HC_EPS_F 1e-6f
#define NORM_EPS_F 1e-6f

typedef __attribute__((ext_vector_type(8))) short short8;
typedef __attribute__((ext_vector_type(4))) float f32x4;

__device__ __forceinline__ float frcp(float v) { return __builtin_amdgcn_rcpf(v); }

// fp32 -> bf16 hi (truncate) + lo (residual, truncate). 3-term MFMA gives ~fp32.
#define CVT_PAIR(j, f0, f1)                                                     \
  { unsigned p0 = __float_as_uint(f0), p1 = __float_as_uint(f1);                \
    H.u[j] = (p1 & 0xFFFF0000u) | (p0 >> 16);                                   \
    unsigned q0 = __float_as_uint((f0) - __uint_as_float(p0 & 0xFFFF0000u));    \
    unsigned q1 = __float_as_uint((f1) - __uint_as_float(p1 & 0xFFFF0000u));    \
    L.u[j] = (q1 & 0xFFFF0000u) | (q0 >> 16); }

__device__ __forceinline__ void cvt_hl(const float4 a, const float4 b,
                                       short8& hi, short8& lo) {
  union { unsigned u[4]; short8 s; } H, L;
  CVT_PAIR(0, a.x, a.y)
  CVT_PAIR(1, a.z, a.w)
  CVT_PAIR(2, b.x, b.y)
  CVT_PAIR(3, b.z, b.w)
  hi = H.s; lo = L.s;
}

// ============ K1: MFMA partial GEMM. 1 wave/block, 16 tok x 512 K-chunk. ============
// w[tok*24 + m] += dot partials (atomic); sq[tok] += sumsq partial (atomic).
__launch_bounds__(64, 4)    // cap 128 VGPR (512/4); demand ~95
__global__ void mhc_dots_mfma(const float* __restrict__ x,
                              const float* __restrict__ hc_fn,
                              float* __restrict__ w,
                              float* __restrict__ sq) {
  const int lane = threadIdx.x;
  const int mt = blockIdx.x >> 3;       // M-tile index
  const int kc = blockIdx.x & 7;        // K-chunk index
  const long long tok0 = (long long)mt * MT;
  const int k0 = kc * KCH;

  const int row = lane & 15;            // A row / B col / C col
  const int ks  = lane >> 4;            // k-slice 0..3 (8 elems each)

  // A: x[tok0+row][k0 + ks*8 + step*32 + 0..7]
  const float4* ap = (const float4*)(x + (tok0 + row) * DDIM + k0) + ks * 2;
  // B tile0: fn rows 0..15 ; tile1: fn rows 16..31 (>=24 invalid -> clamp+zero)
  const float4* bp0 = (const float4*)(hc_fn + (long long)row * DDIM + k0) + ks * 2;
  const int fr1c = (row < 8) ? (16 + row) : 23;   // clamped valid address
  const float4* bp1 = (const float4*)(hc_fn + (long long)fr1c * DDIM + k0) + ks * 2;
  const bool v1 = (row < 8);

  f32x4 acc0 = {0.f, 0.f, 0.f, 0.f};
  f32x4 acc1 = {0.f, 0.f, 0.f, 0.f};
  float ssq = 0.f;
  const float4 z4 = {0.f, 0.f, 0.f, 0.f};

  #pragma unroll
  for (int s = 0; s < KCH / 32; ++s) {  // 16 K-steps of 32
    const float4 a0 = ap[s * 8];
    const float4 a1 = ap[s * 8 + 1];
    const float4 b00 = bp0[s * 8];
    const float4 b01 = bp0[s * 8 + 1];
    float4 b10 = v1 ? bp1[s * 8]     : z4;
    float4 b11 = v1 ? bp1[s * 8 + 1] : z4;

    ssq = fmaf(a0.x, a0.x, fmaf(a0.y, a0.y, fmaf(a0.z, a0.z, fmaf(a0.w, a0.w, ssq))));
    ssq = fmaf(a1.x, a1.x, fmaf(a1.y, a1.y, fmaf(a1.z, a1.z, fmaf(a1.w, a1.w, ssq))));

    short8 ahi, alo, b0hi, b0lo, b1hi, b1lo;
    cvt_hl(a0, a1, ahi, alo);
    cvt_hl(b00, b01, b0hi, b0lo);
    cvt_hl(b10, b11, b1hi, b1lo);

    acc0 = __builtin_amdgcn_mfma_f32_16x16x32_bf16(ahi, b0hi, acc0, 0, 0, 0);
    acc1 = __builtin_amdgcn_mfma_f32_16x16x32_bf16(ahi, b1hi, acc1, 0, 0, 0);
    acc0 = __builtin_amdgcn_mfma_f32_16x16x32_bf16(ahi, b0lo, acc0, 0, 0, 0);
    acc1 = __builtin_amdgcn_mfma_f32_16x16x32_bf16(ahi, b1lo, acc1, 0, 0, 0);
    acc0 = __builtin_amdgcn_mfma_f32_16x16x32_bf16(alo, b0hi, acc0, 0, 0, 0);
    acc1 = __builtin_amdgcn_mfma_f32_16x16x32_bf16(alo, b1hi, acc1, 0, 0, 0);
  }

  // ssq: combine the 4 k-slices of each row (lanes l, l^16, l^32)
  ssq += __shfl_xor(ssq, 16, 64);
  ssq += __shfl_xor(ssq, 32, 64);
  if (lane < 16) atomicAdd(&sq[tok0 + lane], ssq);

  // C: col=lane&15 (m), row=(lane>>4)*4+reg (token) [verified m89 layout]
  const int rq = lane >> 4;
  #pragma unroll
  for (int r = 0; r < 4; ++r)
    atomicAdd(&w[(tok0 + rq * 4 + r) * 24 + row], acc0[r]);
  if (row < 8) {
    #pragma unroll
    for (int r = 0; r < 4; ++r)
      atomicAdd(&w[(tok0 + rq * 4 + r) * 24 + 16 + row], acc1[r]);
  }
}

// ============ K1b: sinkhorn + gates, in-place into w. 16 lanes/token. ============
__launch_bounds__(256, 4)
__global__ void mhc_sinkhorn(float* __restrict__ w,
                             const float* __restrict__ sq,
                             const float* __restrict__ hc_scale,
                             const float* __restrict__ hc_base) {
  const int lane = threadIdx.x & 63;
  const int wave = threadIdx.x >> 6;
  const long long tok = (long long)blockIdx.x * 16 + wave * 4 + (lane >> 4);
  const int e = lane & 15;             // i*4 + j

  float* wt = w + tok * 24;
  const float rs = rsqrtf(sq[tok] * (1.0f / DDIM) + NORM_EPS_F);
  const float s0 = hc_scale[0], s1 = hc_scale[1], s2 = hc_scale[2];

  float h = wt[8 + e] * rs * s2 + hc_base[8 + e];
  // row softmax over j (quad shuffles) + eps
  float mx = fmaxf(h, __shfl_xor(h, 1, 4));
  mx = fmaxf(mx, __shfl_xor(mx, 2, 4));
  float ex = expf(h - mx);
  float sm = ex + __shfl_xor(ex, 1, 4);
  sm += __shfl_xor(sm, 2, 4);
  h = ex * frcp(sm) + HC_EPS_F;
  // column normalize (sum over i: xor 4,8 within 16)
  float cs = h + __shfl_xor(h, 4, 16);
  cs += __shfl_xor(cs, 8, 16);
  h *= frcp(cs + HC_EPS_F);
  #pragma unroll 1
  for (int itn = 0; itn < 19; ++itn) {
    float rsum = h + __shfl_xor(h, 1, 4);
    rsum += __shfl_xor(rsum, 2, 4);
    h *= frcp(rsum + HC_EPS_F);
    float csum = h + __shfl_xor(h, 4, 16);
    csum += __shfl_xor(csum, 8, 16);
    h *= frcp(csum + HC_EPS_F);
  }
  // gate scalars first (reads of wt[0..7] precede the h_res write to wt[8+e])
  float gp = 0.f, gq = 0.f;
  if (e < NS) {
    gp = frcp(1.0f + expf(-(wt[e] * rs * s0 + hc_base[e]))) + HC_EPS_F;
    gq = 2.0f * frcp(1.0f + expf(-(wt[NS + e] * rs * s1 + hc_base[NS + e])));
  }
  wt[8 + e] = h;                       // h_res in-place
  if (e < NS) { wt[e] = gp; wt[NS + e] = gq; }
}

// ============ K2: gates + x -> out (pure stream, at write roofline ~21us) ============
__launch_bounds__(256, 8)
__global__ void mhc_out(const float* __restrict__ x,
                        const float* __restrict__ gates,
                        float* __restrict__ out) {
  const long long token = blockIdx.x;
  const int q = threadIdx.x;           // float4 index in [0,256)

  const float* g = gates + token * 24; // uniform address -> scalar loads
  float hp[NS], hq[NS], hr[NS][NS];
  #pragma unroll
  for (int i = 0; i < NS; ++i) {
    hp[i] = g[i];
    hq[i] = g[NS + i];
    #pragma unroll
    for (int j = 0; j < NS; ++j) hr[i][j] = g[8 + i * NS + j];
  }

  const float4* xb = (const float4*)(x + token * DDIM);
  float4 xv[NS];
  #pragma unroll
  for (int i = 0; i < NS; ++i) xv[i] = xb[i * 256 + q];

  float4 y;
  y.x = hp[0]*xv[0].x + hp[1]*xv[1].x + hp[2]*xv[2].x + hp[3]*xv[3].x;
  y.y = hp[0]*xv[0].y + hp[1]*xv[1].y + hp[2]*xv[2].y + hp[3]*xv[3].y;
  y.z = hp[0]*xv[0].z + hp[1]*xv[1].z + hp[2]*xv[2].z + hp[3]*xv[3].z;
  y.w = hp[0]*xv[0].w + hp[1]*xv[1].w + hp[2]*xv[2].w + hp[3]*xv[3].w;

  float4* ob = (float4*)(out + token * DDIM);
  #pragma unroll
  for (int n = 0; n < NS; ++n) {
    float4 o;
    o.x = hq[n]*y.x + hr[0][n]*xv[0].x + hr[1][n]*xv[1].x + hr[2][n]*xv[2].x + hr[3][n]*xv[3].x;
    o.y = hq[n]*y.y + hr[0][n]*xv[0].y + hr[1][n]*xv[1].y + hr[2][n]*xv[2].y + hr[3][n]*xv[3].y;
    o.z = hq[n]*y.z + hr[0][n]*xv[0].z + hr[1][n]*xv[1].z + hr[2][n]*xv[2].z + hr[3][n]*xv[3].z;
    o.w = hq[n]*y.w + hr[0][n]*xv[0].w + hr[1][n]*xv[1].w + hr[2][n]*xv[2].w + hr[3][n]*xv[3].w;
    ob[n * 256 + q] = o;
  }
}

extern "C" void kernel_launch(void* const* d_in, const int* in_sizes, int n_in,
                              void* d_out, int out_size, void* d_ws, size_t ws_size,
                              hipStream_t stream) {
  const float* x        = (const float*)d_in[0];
  const float* hc_fn    = (const float*)d_in[1];
  const float* hc_scale = (const float*)d_in[2];
  const float* hc_base  = (const float*)d_in[3];
  float* out = (float*)d_out;

  const int ntok = in_sizes[0] / DDIM;       // B*S = 8192
  float* w  = (float*)d_ws;                  // ntok*24 floats = 786432 B (PROVEN size)
  float* sq = out;                           // ssq partials in out[0..ntok) (K2 overwrites)

  hipMemsetAsync(w, 0, (size_t)ntok * 24 * sizeof(float), stream);
  hipMemsetAsync(sq, 0, (size_t)ntok * sizeof(float), stream);

  mhc_dots_mfma<<<(ntok / MT) * 8, 64, 0, stream>>>(x, hc_fn, w, sq);
  mhc_sinkhorn<<<ntok / 16, 256, 0, stream>>>(w, sq, hc_scale, hc_base);
  mhc_out<<<ntok, 256, 0, stream>>>(x, w, out);
}

// Round 13
// 98.500 us; speedup vs baseline: 1.5216x; 1.3219x over previous
//
#include <hip/hip_runtime.h>
#include <math.h>

#define NS 4
#define HDIM 1024
#define DDIM 4096           // NS*HDIM
#define MT 16               // tokens per MFMA tile (one wave)
#define KCH 512             // K-chunk per wave
#define HC_EPS_F 1e-6f
#define NORM_EPS_F 1e-6f

typedef __attribute__((ext_vector_type(8))) short short8;
typedef __attribute__((ext_vector_type(4))) float f32x4;

__device__ __forceinline__ float frcp(float v) { return __builtin_amdgcn_rcpf(v); }

// fp32 -> bf16 hi (truncate) + lo (residual, truncate). 3-term MFMA ~ fp32.
#define CVT_PAIR(j, f0, f1)                                                     \
  { unsigned p0 = __float_as_uint(f0), p1 = __float_as_uint(f1);                \
    H.u[j] = (p1 & 0xFFFF0000u) | (p0 >> 16);                                   \
    unsigned q0 = __float_as_uint((f0) - __uint_as_float(p0 & 0xFFFF0000u));    \
    unsigned q1 = __float_as_uint((f1) - __uint_as_float(p1 & 0xFFFF0000u));    \
    L.u[j] = (q1 & 0xFFFF0000u) | (q0 >> 16); }

__device__ __forceinline__ void cvt_hl(const float4 a, const float4 b,
                                       short8& hi, short8& lo) {
  union { unsigned u[4]; short8 s; } H, L;
  CVT_PAIR(0, a.x, a.y)
  CVT_PAIR(1, a.z, a.w)
  CVT_PAIR(2, b.x, b.y)
  CVT_PAIR(3, b.z, b.w)
  hi = H.s; lo = L.s;
}

// ============ K1: MFMA partial GEMM, 4 independent waves/block, explicit dbuf. ============
// Wave-unit u: mt = u>>3 (16-token tile), kc = u&7 (512-K chunk).
// w[tok*24+m] += partial (atomic); sq[tok] += ssq partial (atomic).
// (256,2) -> VGPR cap 128 (toolchain law, R7-R11). Demand ~100: acc 8 + dbuf 48 + addr/cvt.
__launch_bounds__(256, 2)
__global__ void mhc_dots_mfma(const float* __restrict__ x,
                              const float* __restrict__ hc_fn,
                              float* __restrict__ w,
                              float* __restrict__ sq) {
  const int lane = threadIdx.x & 63;
  const int wave = threadIdx.x >> 6;
  const int wunit = blockIdx.x * 4 + wave;
  const int mt = wunit >> 3;            // M-tile index
  const int kc = wunit & 7;             // K-chunk index
  const long long tok0 = (long long)mt * MT;
  const int k0 = kc * KCH;

  const int row = lane & 15;            // A row / B col / C col
  const int ks  = lane >> 4;            // k-slice 0..3 (8 elems each)

  const float4* ap  = (const float4*)(x + (tok0 + row) * DDIM + k0) + ks * 2;
  const float4* bp0 = (const float4*)(hc_fn + (long long)row * DDIM + k0) + ks * 2;
  const int fr1c = (row < 8) ? (16 + row) : 23;   // clamped valid address
  const float4* bp1 = (const float4*)(hc_fn + (long long)fr1c * DDIM + k0) + ks * 2;
  const bool v1 = (row < 8);
  const float4 z4 = {0.f, 0.f, 0.f, 0.f};

  f32x4 acc0 = {0.f, 0.f, 0.f, 0.f};
  f32x4 acc1 = {0.f, 0.f, 0.f, 0.f};
  float ssq = 0.f;

  // ---- explicit 1-deep double buffer: 6 float4 in flight during each step ----
  float4 ca0 = ap[0],  ca1 = ap[1];
  float4 cb00 = bp0[0], cb01 = bp0[1];
  float4 cb10 = v1 ? bp1[0] : z4, cb11 = v1 ? bp1[1] : z4;

  #pragma unroll 2
  for (int s = 0; s < KCH / 32; ++s) {  // 16 K-steps of 32
    float4 na0, na1, nb00, nb01, nb10, nb11;
    if (s < 15) {
      const int o = (s + 1) * 8;
      na0 = ap[o]; na1 = ap[o + 1];
      nb00 = bp0[o]; nb01 = bp0[o + 1];
      nb10 = v1 ? bp1[o] : z4; nb11 = v1 ? bp1[o + 1] : z4;
    }

    ssq = fmaf(ca0.x, ca0.x, fmaf(ca0.y, ca0.y, fmaf(ca0.z, ca0.z, fmaf(ca0.w, ca0.w, ssq))));
    ssq = fmaf(ca1.x, ca1.x, fmaf(ca1.y, ca1.y, fmaf(ca1.z, ca1.z, fmaf(ca1.w, ca1.w, ssq))));

    short8 ahi, alo, b0hi, b0lo, b1hi, b1lo;
    cvt_hl(ca0, ca1, ahi, alo);
    cvt_hl(cb00, cb01, b0hi, b0lo);
    cvt_hl(cb10, cb11, b1hi, b1lo);

    acc0 = __builtin_amdgcn_mfma_f32_16x16x32_bf16(ahi, b0hi, acc0, 0, 0, 0);
    acc1 = __builtin_amdgcn_mfma_f32_16x16x32_bf16(ahi, b1hi, acc1, 0, 0, 0);
    acc0 = __builtin_amdgcn_mfma_f32_16x16x32_bf16(ahi, b0lo, acc0, 0, 0, 0);
    acc1 = __builtin_amdgcn_mfma_f32_16x16x32_bf16(ahi, b1lo, acc1, 0, 0, 0);
    acc0 = __builtin_amdgcn_mfma_f32_16x16x32_bf16(alo, b0hi, acc0, 0, 0, 0);
    acc1 = __builtin_amdgcn_mfma_f32_16x16x32_bf16(alo, b1hi, acc1, 0, 0, 0);

    if (s < 15) {
      ca0 = na0; ca1 = na1;
      cb00 = nb00; cb01 = nb01;
      cb10 = nb10; cb11 = nb11;
    }
  }

  // ssq: combine the 4 k-slices of each row (lanes l, l^16, l^32)
  ssq += __shfl_xor(ssq, 16, 64);
  ssq += __shfl_xor(ssq, 32, 64);
  if (lane < 16) atomicAdd(&sq[tok0 + lane], ssq);

  // C: col=lane&15 (m), row=(lane>>4)*4+reg (token) [verified m89 layout]
  const int rq = lane >> 4;
  #pragma unroll
  for (int r = 0; r < 4; ++r)
    atomicAdd(&w[(tok0 + rq * 4 + r) * 24 + row], acc0[r]);
  if (row < 8) {
    #pragma unroll
    for (int r = 0; r < 4; ++r)
      atomicAdd(&w[(tok0 + rq * 4 + r) * 24 + 16 + row], acc1[r]);
  }
}

// ============ K1b: sinkhorn + gates, in-place into w. 16 lanes/token. ============
__launch_bounds__(256, 4)
__global__ void mhc_sinkhorn(float* __restrict__ w,
                             const float* __restrict__ sq,
                             const float* __restrict__ hc_scale,
                             const float* __restrict__ hc_base) {
  const int lane = threadIdx.x & 63;
  const int wave = threadIdx.x >> 6;
  const long long tok = (long long)blockIdx.x * 16 + wave * 4 + (lane >> 4);
  const int e = lane & 15;             // i*4 + j

  float* wt = w + tok * 24;
  const float rs = rsqrtf(sq[tok] * (1.0f / DDIM) + NORM_EPS_F);
  const float s0 = hc_scale[0], s1 = hc_scale[1], s2 = hc_scale[2];

  float h = wt[8 + e] * rs * s2 + hc_base[8 + e];
  float mx = fmaxf(h, __shfl_xor(h, 1, 4));
  mx = fmaxf(mx, __shfl_xor(mx, 2, 4));
  float ex = expf(h - mx);
  float sm = ex + __shfl_xor(ex, 1, 4);
  sm += __shfl_xor(sm, 2, 4);
  h = ex * frcp(sm) + HC_EPS_F;
  float cs = h + __shfl_xor(h, 4, 16);
  cs += __shfl_xor(cs, 8, 16);
  h *= frcp(cs + HC_EPS_F);
  #pragma unroll 1
  for (int itn = 0; itn < 19; ++itn) {
    float rsum = h + __shfl_xor(h, 1, 4);
    rsum += __shfl_xor(rsum, 2, 4);
    h *= frcp(rsum + HC_EPS_F);
    float csum = h + __shfl_xor(h, 4, 16);
    csum += __shfl_xor(csum, 8, 16);
    h *= frcp(csum + HC_EPS_F);
  }
  float gp = 0.f, gq = 0.f;
  if (e < NS) {
    gp = frcp(1.0f + expf(-(wt[e] * rs * s0 + hc_base[e]))) + HC_EPS_F;
    gq = 2.0f * frcp(1.0f + expf(-(wt[NS + e] * rs * s1 + hc_base[NS + e])));
  }
  wt[8 + e] = h;
  if (e < NS) { wt[e] = gp; wt[NS + e] = gq; }
}

// ============ K2: gates + x -> out (pure stream, at write roofline ~21us) ============
__launch_bounds__(256, 8)
__global__ void mhc_out(const float* __restrict__ x,
                        const float* __restrict__ gates,
                        float* __restrict__ out) {
  const long long token = blockIdx.x;
  const int q = threadIdx.x;           // float4 index in [0,256)

  const float* g = gates + token * 24; // uniform address -> scalar loads
  float hp[NS], hq[NS], hr[NS][NS];
  #pragma unroll
  for (int i = 0; i < NS; ++i) {
    hp[i] = g[i];
    hq[i] = g[NS + i];
    #pragma unroll
    for (int j = 0; j < NS; ++j) hr[i][j] = g[8 + i * NS + j];
  }

  const float4* xb = (const float4*)(x + token * DDIM);
  float4 xv[NS];
  #pragma unroll
  for (int i = 0; i < NS; ++i) xv[i] = xb[i * 256 + q];

  float4 y;
  y.x = hp[0]*xv[0].x + hp[1]*xv[1].x + hp[2]*xv[2].x + hp[3]*xv[3].x;
  y.y = hp[0]*xv[0].y + hp[1]*xv[1].y + hp[2]*xv[2].y + hp[3]*xv[3].y;
  y.z = hp[0]*xv[0].z + hp[1]*xv[1].z + hp[2]*xv[2].z + hp[3]*xv[3].z;
  y.w = hp[0]*xv[0].w + hp[1]*xv[1].w + hp[2]*xv[2].w + hp[3]*xv[3].w;

  float4* ob = (float4*)(out + token * DDIM);
  #pragma unroll
  for (int n = 0; n < NS; ++n) {
    float4 o;
    o.x = hq[n]*y.x + hr[0][n]*xv[0].x + hr[1][n]*xv[1].x + hr[2][n]*xv[2].x + hr[3][n]*xv[3].x;
    o.y = hq[n]*y.y + hr[0][n]*xv[0].y + hr[1][n]*xv[1].y + hr[2][n]*xv[2].y + hr[3][n]*xv[3].y;
    o.z = hq[n]*y.z + hr[0][n]*xv[0].z + hr[1][n]*xv[1].z + hr[2][n]*xv[2].z + hr[3][n]*xv[3].z;
    o.w = hq[n]*y.w + hr[0][n]*xv[0].w + hr[1][n]*xv[1].w + hr[2][n]*xv[2].w + hr[3][n]*xv[3].w;
    ob[n * 256 + q] = o;
  }
}

extern "C" void kernel_launch(void* const* d_in, const int* in_sizes, int n_in,
                              void* d_out, int out_size, void* d_ws, size_t ws_size,
                              hipStream_t stream) {
  const float* x        = (const float*)d_in[0];
  const float* hc_fn    = (const float*)d_in[1];
  const float* hc_scale = (const float*)d_in[2];
  const float* hc_base  = (const float*)d_in[3];
  float* out = (float*)d_out;

  const int ntok = in_sizes[0] / DDIM;       // B*S = 8192
  float* w  = (float*)d_ws;                  // ntok*24 floats = 786432 B (PROVEN size)
  float* sq = out;                           // ssq partials in out[0..ntok) (K2 overwrites)

  hipMemsetAsync(w, 0, (size_t)ntok * 24 * sizeof(float), stream);
  hipMemsetAsync(sq, 0, (size_t)ntok * sizeof(float), stream);

  const int wave_units = (ntok / MT) * 8;    // 4096
  mhc_dots_mfma<<<wave_units / 4, 256, 0, stream>>>(x, hc_fn, w, sq);
  mhc_sinkhorn<<<ntok / 16, 256, 0, stream>>>(w, sq, hc_scale, hc_base);
  mhc_out<<<ntok, 256, 0, stream>>>(x, w, out);
}

// Round 14
// 95.183 us; speedup vs baseline: 1.5746x; 1.0348x over previous
//
#include <hip/hip_runtime.h>
#include <math.h>

#define NS 4
#define HDIM 1024
#define DDIM 4096           // NS*HDIM
#define MT 16               // tokens per MFMA tile (one wave)
#define KCH 512             // K-chunk per wave (8 chunks over K=4096)
#define NKC 8
#define HC_EPS_F 1e-6f
#define NORM_EPS_F 1e-6f

typedef __attribute__((ext_vector_type(8))) short short8;
typedef __attribute__((ext_vector_type(4))) float f32x4;

__device__ __forceinline__ float frcp(float v) { return __builtin_amdgcn_rcpf(v); }

// fp32 -> bf16 hi (truncate) + lo (residual, truncate). 3-term MFMA ~ fp32.
#define CVT_PAIR(j, f0, f1)                                                     \
  { unsigned p0 = __float_as_uint(f0), p1 = __float_as_uint(f1);                \
    H.u[j] = (p1 & 0xFFFF0000u) | (p0 >> 16);                                   \
    unsigned q0 = __float_as_uint((f0) - __uint_as_float(p0 & 0xFFFF0000u));    \
    unsigned q1 = __float_as_uint((f1) - __uint_as_float(p1 & 0xFFFF0000u));    \
    L.u[j] = (q1 & 0xFFFF0000u) | (q0 >> 16); }

__device__ __forceinline__ void cvt_hl(const float4 a, const float4 b,
                                       short8& hi, short8& lo) {
  union { unsigned u[4]; short8 s; } H, L;
  CVT_PAIR(0, a.x, a.y)
  CVT_PAIR(1, a.z, a.w)
  CVT_PAIR(2, b.x, b.y)
  CVT_PAIR(3, b.z, b.w)
  hi = H.s; lo = L.s;
}

// ============ K1: MFMA partial GEMM, 2-deep reg pipeline, direct partial stores. ============
// wp[kc][tok][25] lives in OUT (scratch; K2 fully overwrites out afterwards).
// Uncapped regs (256,1): named-var 2-deep dbuf must stay in registers (R12: caps fold it).
__launch_bounds__(256, 1)
__global__ void mhc_dots_mfma(const float* __restrict__ x,
                              const float* __restrict__ hc_fn,
                              float* __restrict__ wp, int ntok) {
  const int lane = threadIdx.x & 63;
  const int wave = threadIdx.x >> 6;
  const int wunit = blockIdx.x * 4 + wave;
  const int mt = wunit >> 3;            // M-tile index
  const int kc = wunit & 7;             // K-chunk index
  const long long tok0 = (long long)mt * MT;
  const int k0 = kc * KCH;

  const int row = lane & 15;            // A row / B col / C col
  const int ks  = lane >> 4;            // k-slice 0..3 (8 elems each)

  const float4* ap  = (const float4*)(x + (tok0 + row) * DDIM + k0) + ks * 2;
  const float4* bp0 = (const float4*)(hc_fn + (long long)row * DDIM + k0) + ks * 2;
  const int fr1c = (row < 8) ? (16 + row) : 23;   // clamped valid address
  const float4* bp1 = (const float4*)(hc_fn + (long long)fr1c * DDIM + k0) + ks * 2;
  const bool v1 = (row < 8);
  const float4 z4 = {0.f, 0.f, 0.f, 0.f};

  f32x4 acc0 = {0.f, 0.f, 0.f, 0.f};
  f32x4 acc1 = {0.f, 0.f, 0.f, 0.f};
  float ssq = 0.f;

  // ---- explicit 2-deep pipeline, all stage vars NAMED (never runtime-indexed) ----
  float4 a0_c = ap[0], a1_c = ap[1];
  float4 b00_c = bp0[0], b01_c = bp0[1];
  float4 b10_c = v1 ? bp1[0] : z4, b11_c = v1 ? bp1[1] : z4;
  float4 a0_n = ap[8], a1_n = ap[9];
  float4 b00_n = bp0[8], b01_n = bp0[9];
  float4 b10_n = v1 ? bp1[8] : z4, b11_n = v1 ? bp1[9] : z4;

  #pragma unroll 4
  for (int s = 0; s < KCH / 32; ++s) {  // 16 K-steps of 32
    float4 a0_p, a1_p, b00_p, b01_p, b10_p, b11_p;
    if (s < 14) {
      const int o = (s + 2) * 8;
      a0_p = ap[o]; a1_p = ap[o + 1];
      b00_p = bp0[o]; b01_p = bp0[o + 1];
      b10_p = v1 ? bp1[o] : z4; b11_p = v1 ? bp1[o + 1] : z4;
    }

    ssq = fmaf(a0_c.x, a0_c.x, fmaf(a0_c.y, a0_c.y, fmaf(a0_c.z, a0_c.z, fmaf(a0_c.w, a0_c.w, ssq))));
    ssq = fmaf(a1_c.x, a1_c.x, fmaf(a1_c.y, a1_c.y, fmaf(a1_c.z, a1_c.z, fmaf(a1_c.w, a1_c.w, ssq))));

    short8 ahi, alo, b0hi, b0lo, b1hi, b1lo;
    cvt_hl(a0_c, a1_c, ahi, alo);
    cvt_hl(b00_c, b01_c, b0hi, b0lo);
    cvt_hl(b10_c, b11_c, b1hi, b1lo);

    acc0 = __builtin_amdgcn_mfma_f32_16x16x32_bf16(ahi, b0hi, acc0, 0, 0, 0);
    acc1 = __builtin_amdgcn_mfma_f32_16x16x32_bf16(ahi, b1hi, acc1, 0, 0, 0);
    acc0 = __builtin_amdgcn_mfma_f32_16x16x32_bf16(ahi, b0lo, acc0, 0, 0, 0);
    acc1 = __builtin_amdgcn_mfma_f32_16x16x32_bf16(ahi, b1lo, acc1, 0, 0, 0);
    acc0 = __builtin_amdgcn_mfma_f32_16x16x32_bf16(alo, b0hi, acc0, 0, 0, 0);
    acc1 = __builtin_amdgcn_mfma_f32_16x16x32_bf16(alo, b1hi, acc1, 0, 0, 0);

    if (s < 15) {
      a0_c = a0_n; a1_c = a1_n;
      b00_c = b00_n; b01_c = b01_n;
      b10_c = b10_n; b11_c = b11_n;
    }
    if (s < 14) {
      a0_n = a0_p; a1_n = a1_p;
      b00_n = b00_p; b01_n = b01_p;
      b10_n = b10_p; b11_n = b11_p;
    }
  }

  // ssq: combine the 4 k-slices of each row (lanes l, l^16, l^32)
  ssq += __shfl_xor(ssq, 16, 64);
  ssq += __shfl_xor(ssq, 32, 64);

  // direct partial stores (no atomics): wp[kc][tok][25]
  float* wpk = wp + (long long)kc * ntok * 25;
  if (lane < 16) wpk[(tok0 + lane) * 25 + 24] = ssq;
  const int rq = lane >> 4;
  #pragma unroll
  for (int r = 0; r < 4; ++r)
    wpk[(tok0 + rq * 4 + r) * 25 + row] = acc0[r];
  if (row < 8) {
    #pragma unroll
    for (int r = 0; r < 4; ++r)
      wpk[(tok0 + rq * 4 + r) * 25 + 16 + row] = acc1[r];
  }
}

// ============ K1b: reduce partials + sinkhorn -> gates[tok][24]. ============
__launch_bounds__(256, 4)
__global__ void mhc_sinkhorn(const float* __restrict__ wp,
                             const float* __restrict__ hc_scale,
                             const float* __restrict__ hc_base,
                             float* __restrict__ gates, int ntok) {
  const int lane = threadIdx.x & 63;
  const int wave = threadIdx.x >> 6;
  const long long tok = (long long)blockIdx.x * 16 + wave * 4 + (lane >> 4);
  const int e = lane & 15;             // i*4 + j

  // reduce the 8 K-chunk partials
  const long long kstride = (long long)ntok * 25;
  const float* b = wp + tok * 25;
  float sres = 0.f, ssq = 0.f, spre = 0.f, spost = 0.f;
  #pragma unroll
  for (int kc = 0; kc < NKC; ++kc) {
    const float* p = b + kc * kstride;
    sres += p[8 + e];
    ssq  += p[24];
    if (e < NS) { spre += p[e]; spost += p[NS + e]; }
  }

  const float rs = rsqrtf(ssq * (1.0f / DDIM) + NORM_EPS_F);
  const float s0 = hc_scale[0], s1 = hc_scale[1], s2 = hc_scale[2];

  float h = sres * rs * s2 + hc_base[8 + e];
  float mx = fmaxf(h, __shfl_xor(h, 1, 4));
  mx = fmaxf(mx, __shfl_xor(mx, 2, 4));
  float ex = expf(h - mx);
  float sm = ex + __shfl_xor(ex, 1, 4);
  sm += __shfl_xor(sm, 2, 4);
  h = ex * frcp(sm) + HC_EPS_F;
  float cs = h + __shfl_xor(h, 4, 16);
  cs += __shfl_xor(cs, 8, 16);
  h *= frcp(cs + HC_EPS_F);
  #pragma unroll 1
  for (int itn = 0; itn < 19; ++itn) {
    float rsum = h + __shfl_xor(h, 1, 4);
    rsum += __shfl_xor(rsum, 2, 4);
    h *= frcp(rsum + HC_EPS_F);
    float csum = h + __shfl_xor(h, 4, 16);
    csum += __shfl_xor(csum, 8, 16);
    h *= frcp(csum + HC_EPS_F);
  }
  float* g = gates + tok * 24;
  g[8 + e] = h;
  if (e < NS) {
    g[e] = frcp(1.0f + expf(-(spre * rs * s0 + hc_base[e]))) + HC_EPS_F;
    g[NS + e] = 2.0f * frcp(1.0f + expf(-(spost * rs * s1 + hc_base[NS + e])));
  }
}

// ============ K2: gates + x -> out (pure stream, at write roofline ~21us) ============
__launch_bounds__(256, 8)
__global__ void mhc_out(const float* __restrict__ x,
                        const float* __restrict__ gates,
                        float* __restrict__ out) {
  const long long token = blockIdx.x;
  const int q = threadIdx.x;           // float4 index in [0,256)

  const float* g = gates + token * 24; // uniform address -> scalar loads
  float hp[NS], hq[NS], hr[NS][NS];
  #pragma unroll
  for (int i = 0; i < NS; ++i) {
    hp[i] = g[i];
    hq[i] = g[NS + i];
    #pragma unroll
    for (int j = 0; j < NS; ++j) hr[i][j] = g[8 + i * NS + j];
  }

  const float4* xb = (const float4*)(x + token * DDIM);
  float4 xv[NS];
  #pragma unroll
  for (int i = 0; i < NS; ++i) xv[i] = xb[i * 256 + q];

  float4 y;
  y.x = hp[0]*xv[0].x + hp[1]*xv[1].x + hp[2]*xv[2].x + hp[3]*xv[3].x;
  y.y = hp[0]*xv[0].y + hp[1]*xv[1].y + hp[2]*xv[2].y + hp[3]*xv[3].y;
  y.z = hp[0]*xv[0].z + hp[1]*xv[1].z + hp[2]*xv[2].z + hp[3]*xv[3].z;
  y.w = hp[0]*xv[0].w + hp[1]*xv[1].w + hp[2]*xv[2].w + hp[3]*xv[3].w;

  float4* ob = (float4*)(out + token * DDIM);
  #pragma unroll
  for (int n = 0; n < NS; ++n) {
    float4 o;
    o.x = hq[n]*y.x + hr[0][n]*xv[0].x + hr[1][n]*xv[1].x + hr[2][n]*xv[2].x + hr[3][n]*xv[3].x;
    o.y = hq[n]*y.y + hr[0][n]*xv[0].y + hr[1][n]*xv[1].y + hr[2][n]*xv[2].y + hr[3][n]*xv[3].y;
    o.z = hq[n]*y.z + hr[0][n]*xv[0].z + hr[1][n]*xv[1].z + hr[2][n]*xv[2].z + hr[3][n]*xv[3].z;
    o.w = hq[n]*y.w + hr[0][n]*xv[0].w + hr[1][n]*xv[1].w + hr[2][n]*xv[2].w + hr[3][n]*xv[3].w;
    ob[n * 256 + q] = o;
  }
}

extern "C" void kernel_launch(void* const* d_in, const int* in_sizes, int n_in,
                              void* d_out, int out_size, void* d_ws, size_t ws_size,
                              hipStream_t stream) {
  const float* x        = (const float*)d_in[0];
  const float* hc_fn    = (const float*)d_in[1];
  const float* hc_scale = (const float*)d_in[2];
  const float* hc_base  = (const float*)d_in[3];
  float* out = (float*)d_out;

  const int ntok = in_sizes[0] / DDIM;       // B*S = 8192
  float* gates = (float*)d_ws;               // ntok*24*4 = 786 KB (PROVEN within ws_size)
  float* wp    = out;                        // partials wp[8][ntok][25] = 6.5 MB, scratch in out;
                                             // K2 fully overwrites out afterwards.

  const int wave_units = (ntok / MT) * NKC;  // 4096
  mhc_dots_mfma<<<wave_units / 4, 256, 0, stream>>>(x, hc_fn, wp, ntok);
  mhc_sinkhorn<<<ntok / 16, 256, 0, stream>>>(wp, hc_scale, hc_base, gates, ntok);
  mhc_out<<<ntok, 256, 0, stream>>>(x, gates, out);
}